// Round 8
// baseline (264.263 us; speedup 1.0000x reference)
//
#include <hip/hip_runtime.h>
#include <hip/hip_bf16.h>

typedef __attribute__((ext_vector_type(8))) short short8;
typedef __attribute__((ext_vector_type(4))) float floatx4;
typedef __attribute__((ext_vector_type(4))) unsigned int uintx4;

#define OVCAP 65536

// fast GELU: x * (1 - 1/(exp(2u)+1)), u = 0.79788456*(x + 0.044715 x^3)
__device__ __forceinline__ float gelu_fast(float x)
{
    float u = 0.7978845608f * x * (1.0f + 0.044715f * x * x);
    float e = __builtin_amdgcn_exp2f(2.885390082f * u);   // exp(2u)
    return x - x * __builtin_amdgcn_rcpf(e + 1.0f);
}

// prep: [0,T): count triangles per dst; first 6 arrivals per dst go to the
// direct-mapped table pad6[dst*6+slot] (records are pre-scaled byte offsets
// i<<8); later arrivals go to a bump-allocated overflow pool chained per-dst
// via atomicExch on ovh (head index biased +1, 0 = end => zero-memset init).
// [T,T+6144): fragment-ordered bf16 W (frag f=ko*8+nt over global ko 0..11,
// lane l: 8 elems W[ko*32+quad*8+j][nt*16+col]).
__global__ __launch_bounds__(256)
void prep(const float* __restrict__ Wg, uintx4* __restrict__ wq,
          const int* __restrict__ tri, int* __restrict__ cnt,
          int* __restrict__ ovh, int4* __restrict__ nodes,
          int* __restrict__ ovc, int2* __restrict__ pad6, int T)
{
    int g = blockIdx.x * 256 + threadIdx.x;
    if (g < T) {
        int i0 = tri[g * 3 + 0];
        int i1 = tri[g * 3 + 1];
        int i2 = tri[g * 3 + 2];
        int sl = atomicAdd(&cnt[i2], 1);
        if (sl < 6) {
            pad6[(size_t)i2 * 6 + sl] = make_int2(i0 << 8, i1 << 8);
        } else {
            int idx = atomicAdd(ovc, 1);
            if (idx < OVCAP) {
                int prev = atomicExch(&ovh[i2], idx + 1);
                nodes[idx] = make_int4(prev, i0 << 8, i1 << 8, 0);
            }
        }
    } else {
        int i = g - T;
        if (i < 6144) {
            int frag = i >> 6, lane = i & 63;
            int ko = frag >> 3, nt = frag & 7;
            int col = lane & 15, quad = lane >> 4;
            unsigned short tmp[8] __attribute__((aligned(16)));
#pragma unroll
            for (int j = 0; j < 8; ++j) {
                __hip_bfloat16 b =
                    __float2bfloat16(Wg[(ko * 32 + quad * 8 + j) * 128 + nt * 16 + col]);
                tmp[j] = *(unsigned short*)&b;
            }
            wq[i] = *(const uintx4*)tmp;
        }
    }
}

// One-pass dense GEMM: all 3 W slices resident in 96KB LDS; A tile loaded and
// converted once, used for r=0,1,2. Output bf16, permuted C-layout (row i:
// physical elem col*8+nt = logical col nt*16+col). No barriers in main loop.
__global__ __launch_bounds__(1024, 1)
void edge_gemm(const float* __restrict__ fe_f, const uintx4* __restrict__ wq,
               unsigned short* __restrict__ G, int E)
{
    __shared__ uintx4 ldsW[6144];   // 96 KB: 12 global-ko x 8 nt fragment blocks

    const int tid  = threadIdx.x;
    const int wv   = tid >> 6;
    const int lane = tid & 63;
    const int col  = lane & 15;
    const int quad = lane >> 4;
    const int ntiles = (E + 15) >> 4;

    for (int i = tid; i < 6144; i += 1024) ldsW[i] = wq[i];
    __syncthreads();

#pragma unroll 1
    for (int tile = blockIdx.x * 16 + wv; tile < ntiles; tile += gridDim.x * 16) {
        int row_a = tile * 16 + col;
        if (row_a >= E) row_a = E - 1;
        const float* arow = fe_f + (size_t)row_a * 128 + quad * 8;

        floatx4 f[8];
#pragma unroll
        for (int l = 0; l < 8; ++l)
            f[l] = *(const floatx4*)(arow + (l >> 1) * 32 + (l & 1) * 4);

        short8 a[4];
#pragma unroll
        for (int ko = 0; ko < 4; ++ko) {
            unsigned short tmp[8] __attribute__((aligned(16)));
#pragma unroll
            for (int j = 0; j < 8; ++j) {
                __hip_bfloat16 b = __float2bfloat16(f[ko * 2 + (j >> 2)][j & 3]);
                tmp[j] = *(unsigned short*)&b;
            }
            a[ko] = *(const short8*)tmp;
        }

#pragma unroll 1
        for (int r = 0; r < 3; ++r) {
            floatx4 acc[8];
#pragma unroll
            for (int nt = 0; nt < 8; ++nt) acc[nt] = (floatx4)0.0f;

#pragma unroll
            for (int ko = 0; ko < 4; ++ko) {
#pragma unroll
                for (int nt = 0; nt < 8; ++nt) {
                    short8 bf = *(const short8*)&ldsW[r * 2048 + (ko * 8 + nt) * 64 + lane];
                    acc[nt] = __builtin_amdgcn_mfma_f32_16x16x32_bf16(a[ko], bf, acc[nt], 0, 0, 0);
                }
            }

            unsigned short* Gr = G + (size_t)r * E * 128;
#pragma unroll
            for (int rr = 0; rr < 4; ++rr) {
                int row = tile * 16 + quad * 4 + rr;
                if (row < E) {
                    unsigned short pk[8] __attribute__((aligned(16)));
#pragma unroll
                    for (int nt = 0; nt < 8; ++nt) {
                        __hip_bfloat16 hb = __float2bfloat16(acc[nt][rr]);
                        pk[nt] = *(unsigned short*)&hb;
                    }
                    *(uintx4*)(Gr + (size_t)row * 128 + col * 8) = *(const uintx4*)pk;
                }
            }
        }
    }
}

// Per-edge fused gather + GELU + mean + LayerNorm, direct-mapped table.
// depth 1 = {48B uniform header (6 records), cnt, ovh, w2, LN params} -- all
// independent; depth 2 = 12 gathers (addresses for j>=c clamped to 0, their
// contribution predicated out); then 6 GELU steps. Rows with c>6 (11%) walk
// the overflow list (uniform scalar chain, avg 1.8 nodes). No CSR, no srec.
// Lane (col,q) covers logical cols j0=32q+col, j1=j0+16 (permuted layout).
__global__ __launch_bounds__(256)
void mean_ln(const unsigned short* __restrict__ G, const int* __restrict__ cnt,
             const int* __restrict__ ovh, const int4* __restrict__ nodes,
             const int2* __restrict__ pad6, const float* __restrict__ bias,
             const float* __restrict__ gamma, const float* __restrict__ beta,
             float* __restrict__ out, int E)
{
    int lane = threadIdx.x & 63;
    int row  = blockIdx.x * 4 + (threadIdx.x >> 6);
    if (row >= E) return;
    int urow = __builtin_amdgcn_readfirstlane(row);
    int col = lane & 15, q = lane >> 4;
    int boff = (col << 4) + (q << 2);   // byte offset within 256B row
    const char* g0 = (const char*)G + boff;
    const char* g1 = g0 + (size_t)E * 256;
    const char* g2 = g1 + (size_t)E * 256;
    int j0 = q * 32 + col, j1 = j0 + 16;

    // depth-1 independent loads
    const int2* hp = pad6 + (size_t)urow * 6;
    int2 r[6];
#pragma unroll
    for (int j = 0; j < 6; ++j) r[j] = hp[j];
    int c = cnt[urow];
    int h = ovh[urow];
    unsigned int w2 = *(const unsigned int*)(g2 + (size_t)urow * 256);
    float bv0 = bias[j0], bv1 = bias[j1];
    float gm0 = gamma[j0], gm1 = gamma[j1];
    float bt0 = beta[j0],  bt1 = beta[j1];

    const unsigned int M = 0xffffff00u;
    float base0 = __uint_as_float(w2 << 16) + bv0;
    float base1 = __uint_as_float(w2 & 0xffff0000u) + bv1;

    // depth-2: 12 gathers, clamped addresses for unused slots
    unsigned int w0[6], w1[6];
#pragma unroll
    for (int j = 0; j < 6; ++j) {
        unsigned int a0 = (j < c) ? ((unsigned)r[j].x & M) : 0u;
        unsigned int a1 = (j < c) ? ((unsigned)r[j].y & M) : 0u;
        w0[j] = *(const unsigned int*)(g0 + (size_t)a0);
        w1[j] = *(const unsigned int*)(g1 + (size_t)a1);
    }

    float x0 = 0.0f, x1 = 0.0f;
#pragma unroll
    for (int j = 0; j < 6; ++j) {
        bool ok = j < c;
        float s0 = __uint_as_float(w0[j] << 16)
                 + __uint_as_float(w1[j] << 16) + base0;
        float s1 = __uint_as_float(w0[j] & 0xffff0000u)
                 + __uint_as_float(w1[j] & 0xffff0000u) + base1;
        x0 += ok ? gelu_fast(s0) : 0.0f;
        x1 += ok ? gelu_fast(s1) : 0.0f;
    }

    // overflow list walk (c > 6, ~11% of rows; head/next biased +1, 0 = end)
    while (h > 0) {
        int4 nd = nodes[h - 1];
        unsigned int u0 = *(const unsigned int*)(g0 + (size_t)(unsigned)nd.y);
        unsigned int u1 = *(const unsigned int*)(g1 + (size_t)(unsigned)nd.z);
        float s0 = __uint_as_float(u0 << 16)
                 + __uint_as_float(u1 << 16) + base0;
        float s1 = __uint_as_float(u0 & 0xffff0000u)
                 + __uint_as_float(u1 & 0xffff0000u) + base1;
        x0 += gelu_fast(s0);
        x1 += gelu_fast(s1);
        h = __builtin_amdgcn_readfirstlane(nd.x);
    }

    float inv = 1.0f / fmaxf((float)c, 1.0f);
    float m0 = x0 * inv, m1 = x1 * inv;
    float sm = m0 + m1;
#pragma unroll
    for (int o = 32; o > 0; o >>= 1) sm += __shfl_xor(sm, o);
    float mu = sm * (1.0f / 128.0f);
    float d0 = m0 - mu, d1 = m1 - mu;
    float v = d0 * d0 + d1 * d1;
#pragma unroll
    for (int o = 32; o > 0; o >>= 1) v += __shfl_xor(v, o);
    float rstd = rsqrtf(v * (1.0f / 128.0f) + 1e-5f);
    __builtin_nontemporal_store(d0 * rstd * gm0 + bt0, &out[(size_t)urow * 128 + j0]);
    __builtin_nontemporal_store(d1 * rstd * gm1 + bt1, &out[(size_t)urow * 128 + j1]);
}

extern "C" void kernel_launch(void* const* d_in, const int* in_sizes, int n_in,
                              void* d_out, int out_size, void* d_ws, size_t ws_size,
                              hipStream_t stream)
{
    const float* fe_f  = (const float*)d_in[0];
    const float* Wg    = (const float*)d_in[1];
    const float* bias  = (const float*)d_in[2];
    const float* gamma = (const float*)d_in[3];
    const float* beta  = (const float*)d_in[4];
    const int*   tri   = (const int*)d_in[5];

    int E = in_sizes[0] / 128;
    int T = in_sizes[5] / 3;

    // ws: G (3*E*256 B) | pad6 (E*6 int2) | nodes (OVCAP int4) | cnt (E) |
    //     ovh (E) | ovc (64B) | wq (96KB)   -- total 83.55 MB < proven 83.70
    char* p = (char*)d_ws;
    unsigned short* G = (unsigned short*)p;  p += (size_t)3 * E * 256;
    int2* pad6 = (int2*)p;                   p += (size_t)E * 48;
    int4* nodes = (int4*)p;                  p += (size_t)OVCAP * 16;
    int* cnt = (int*)p;                      p += (size_t)E * 4;
    int* ovh = (int*)p;                      p += (size_t)E * 4;
    int* ovc = (int*)p;                      p += 64;
    uintx4* wq = (uintx4*)p;

    // zero cnt + ovh + ovc (contiguous); pad6/nodes need no init (addresses
    // for unused slots are clamped in mean_ln)
    (void)hipMemsetAsync(cnt, 0, (size_t)E * 8 + 64, stream);

    int total = T + 6144;
    prep<<<(total + 255) / 256, 256, 0, stream>>>(Wg, wq, tri, cnt, ovh, nodes,
                                                  ovc, pad6, T);

    edge_gemm<<<256, 1024, 0, stream>>>(fe_f, wq, G, E);

    mean_ln<<<(E + 3) / 4, 256, 0, stream>>>(G, cnt, ovh, nodes, pad6,
                                             bias, gamma, beta, (float*)d_out, E);
}

// Round 9
// 215.725 us; speedup vs baseline: 1.2250x; 1.2250x over previous
//
#include <hip/hip_runtime.h>
#include <hip/hip_bf16.h>

typedef __attribute__((ext_vector_type(8))) short short8;
typedef __attribute__((ext_vector_type(4))) float floatx4;
typedef __attribute__((ext_vector_type(4))) unsigned int uintx4;

// fast GELU: x * (1 - 1/(exp(2u)+1)), u = 0.79788456*(x + 0.044715 x^3)
__device__ __forceinline__ float gelu_fast(float x)
{
    float u = 0.7978845608f * x * (1.0f + 0.044715f * x * x);
    float e = __builtin_amdgcn_exp2f(2.885390082f * u);   // exp(2u)
    return x - x * __builtin_amdgcn_rcpf(e + 1.0f);
}

// prep: [0,T): count triangles per dst, record slot; [T,T+6144): fragment-
// ordered bf16 W (frag f=ko*8+nt over global ko 0..11, lane l: 8 elems
// W[ko*32+quad*8+j][nt*16+col]).
__global__ __launch_bounds__(256)
void prep(const float* __restrict__ Wg, uintx4* __restrict__ wq,
          const int* __restrict__ tri, int* __restrict__ cnt,
          int* __restrict__ slot, int T)
{
    int g = blockIdx.x * 256 + threadIdx.x;
    if (g < T) {
        int i2 = tri[g * 3 + 2];
        slot[g] = atomicAdd(&cnt[i2], 1);
    } else {
        int i = g - T;
        if (i < 6144) {
            int frag = i >> 6, lane = i & 63;
            int ko = frag >> 3, nt = frag & 7;
            int col = lane & 15, quad = lane >> 4;
            unsigned short tmp[8] __attribute__((aligned(16)));
#pragma unroll
            for (int j = 0; j < 8; ++j) {
                __hip_bfloat16 b =
                    __float2bfloat16(Wg[(ko * 32 + quad * 8 + j) * 128 + nt * 16 + col]);
                tmp[j] = *(unsigned short*)&b;
            }
            wq[i] = *(const uintx4*)tmp;
        }
    }
}

__device__ __forceinline__ int wave_incl_scan(int v, int lane)
{
#pragma unroll
    for (int o = 1; o < 64; o <<= 1) {
        int u = __shfl_up(v, o);
        if (lane >= o) v += u;
    }
    return v;
}

// Block-level exclusive scan of 1024 elements; writes per-element exclusive
// prefix (within block) and block total to partial[] (if non-null).
__global__ __launch_bounds__(1024)
void scan_blk(const int* __restrict__ in, int* __restrict__ outExcl,
              int* __restrict__ partial, int n)
{
    __shared__ int ws[16];
    int t = threadIdx.x;
    int g = blockIdx.x * 1024 + t;
    int lane = t & 63, wv = t >> 6;
    int v = (g < n) ? in[g] : 0;
    int sc = wave_incl_scan(v, lane);
    if (lane == 63) ws[wv] = sc;
    __syncthreads();
    if (wv == 0) {
        int b = (lane < 16) ? ws[lane] : 0;
        int bs = wave_incl_scan(b, lane);
        if (lane < 16) ws[lane] = bs;
    }
    __syncthreads();
    int off = wv ? ws[wv - 1] : 0;
    if (g < n) outExcl[g] = off + sc - v;
    if (partial && t == 0) partial[blockIdx.x] = ws[15];
}

// Scatter triangles into dst-sorted order (pre-scaled byte offsets); also emit
// rowinfo = {start, cnt} per edge and zero-pad srec[T..T+7].
__global__ __launch_bounds__(256)
void scatter(const int* __restrict__ tri, const int* __restrict__ slot,
             const int* __restrict__ excl, const int* __restrict__ pscan,
             const int* __restrict__ cnt, int2* __restrict__ srec,
             int2* __restrict__ rowinfo, int E, int T)
{
    int g = blockIdx.x * 256 + threadIdx.x;
    if (g < T) {
        int i0 = tri[g * 3 + 0];
        int i1 = tri[g * 3 + 1];
        int i2 = tri[g * 3 + 2];
        int pos = excl[i2] + pscan[i2 >> 10] + slot[g];
        srec[pos] = make_int2(i0 << 8, i1 << 8);   // byte offsets into G rows
    }
    if (g < E)
        rowinfo[g] = make_int2(excl[g] + pscan[g >> 10], cnt[g]);
    if (g < 8)
        srec[T + g] = make_int2(0, 0);
}

// One-pass dense GEMM: all 3 W slices resident in 96KB LDS; A tile loaded and
// converted once, used for r=0,1,2. Output bf16, permuted C-layout (row i:
// physical elem col*8+nt = logical col nt*16+col). No barriers in main loop.
__global__ __launch_bounds__(1024, 1)
void edge_gemm(const float* __restrict__ fe_f, const uintx4* __restrict__ wq,
               unsigned short* __restrict__ G, int E)
{
    __shared__ uintx4 ldsW[6144];   // 96 KB: 12 global-ko x 8 nt fragment blocks

    const int tid  = threadIdx.x;
    const int wv   = tid >> 6;
    const int lane = tid & 63;
    const int col  = lane & 15;
    const int quad = lane >> 4;
    const int ntiles = (E + 15) >> 4;

    for (int i = tid; i < 6144; i += 1024) ldsW[i] = wq[i];
    __syncthreads();

#pragma unroll 1
    for (int tile = blockIdx.x * 16 + wv; tile < ntiles; tile += gridDim.x * 16) {
        int row_a = tile * 16 + col;
        if (row_a >= E) row_a = E - 1;
        const float* arow = fe_f + (size_t)row_a * 128 + quad * 8;

        floatx4 f[8];
#pragma unroll
        for (int l = 0; l < 8; ++l)
            f[l] = *(const floatx4*)(arow + (l >> 1) * 32 + (l & 1) * 4);

        short8 a[4];
#pragma unroll
        for (int ko = 0; ko < 4; ++ko) {
            unsigned short tmp[8] __attribute__((aligned(16)));
#pragma unroll
            for (int j = 0; j < 8; ++j) {
                __hip_bfloat16 b = __float2bfloat16(f[ko * 2 + (j >> 2)][j & 3]);
                tmp[j] = *(unsigned short*)&b;
            }
            a[ko] = *(const short8*)tmp;
        }

#pragma unroll 1
        for (int r = 0; r < 3; ++r) {
            floatx4 acc[8];
#pragma unroll
            for (int nt = 0; nt < 8; ++nt) acc[nt] = (floatx4)0.0f;

#pragma unroll
            for (int ko = 0; ko < 4; ++ko) {
#pragma unroll
                for (int nt = 0; nt < 8; ++nt) {
                    short8 bf = *(const short8*)&ldsW[r * 2048 + (ko * 8 + nt) * 64 + lane];
                    acc[nt] = __builtin_amdgcn_mfma_f32_16x16x32_bf16(a[ko], bf, acc[nt], 0, 0, 0);
                }
            }

            unsigned short* Gr = G + (size_t)r * E * 128;
#pragma unroll
            for (int rr = 0; rr < 4; ++rr) {
                int row = tile * 16 + quad * 4 + rr;
                if (row < E) {
                    unsigned short pk[8] __attribute__((aligned(16)));
#pragma unroll
                    for (int nt = 0; nt < 8; ++nt) {
                        __hip_bfloat16 hb = __float2bfloat16(acc[nt][rr]);
                        pk[nt] = *(unsigned short*)&hb;
                    }
                    *(uintx4*)(Gr + (size_t)row * 128 + col * 8) = *(const uintx4*)pk;
                }
            }
        }
    }
}

// Per-edge fused gather + GELU + mean + LayerNorm, QUARTER-WAVE rows:
// 16 lanes per row, 4 rows per wave. One gather inst = 16B/lane = 4 full
// triangle row-reads (one per quarter) -> VMEM insts/triangle = 0.5 (was 2),
// and each wave interleaves 4 independent row chains (4-deep latency ILP).
// Records: lanes s&3 load 4 consecutive CSR records in one inst; __shfl from
// lane h*16+k distributes (LDS pipe). Lane (h,s): row = grp*4+h; its 16B
// slice holds phys elems s*8..s*8+7 = logical cols j = k*16+s, k=0..7.
// Grid-stride amortizes bias/gamma/beta prologue over ~3 groups/wave.
__global__ __launch_bounds__(256)
void mean_ln(const unsigned short* __restrict__ G, const int2* __restrict__ rowinfo,
             const int2* __restrict__ srec, const float* __restrict__ bias,
             const float* __restrict__ gamma, const float* __restrict__ beta,
             float* __restrict__ out, int E)
{
    const int tid  = threadIdx.x;
    const int lane = tid & 63;
    const int wid  = tid >> 6;
    const int h    = lane >> 4;    // quarter (row within group)
    const int s    = lane & 15;    // sub-lane within row

    const char* g0 = (const char*)G + s * 16;
    const char* g1 = g0 + (size_t)E * 256;
    const char* g2 = g1 + (size_t)E * 256;

    // params for j = k*16 + s (row-independent, hoisted out of group loop)
    float bv[8], gm[8], bt[8];
#pragma unroll
    for (int k = 0; k < 8; ++k) {
        bv[k] = bias[k * 16 + s];
        gm[k] = gamma[k * 16 + s];
        bt[k] = beta[k * 16 + s];
    }

    const int ngroups = (E + 3) >> 2;
    const int nwaves  = gridDim.x * 4;

    for (int grp = blockIdx.x * 4 + wid; grp < ngroups; grp += nwaves) {
        int row  = grp * 4 + h;
        int rowc = row < E ? row : E - 1;

        int2 ri = rowinfo[rowc];
        int start = ri.x, c = ri.y;

        // cmax over the 4 quarters (c is uniform within a quarter)
        int cmax = max(c, __shfl_xor(c, 16));
        cmax = max(cmax, __shfl_xor(cmax, 32));

        // G2 row slice (16B = this lane's 8 cols) + bias -> base[8]
        uintx4 w2 = *(const uintx4*)(g2 + (size_t)rowc * 256);
        float base[8];
#pragma unroll
        for (int k = 0; k < 8; ++k) {
            unsigned int wv = (k & 1) ? (w2[k >> 1] & 0xffff0000u)
                                      : (w2[k >> 1] << 16);
            base[k] = __uint_as_float(wv) + bv[k];
        }

        float x[8];
#pragma unroll
        for (int k = 0; k < 8; ++k) x[k] = 0.0f;

        for (int t = 0; t < cmax; t += 4) {
            // lanes s&3 of each quarter fetch records t..t+3 (clamped)
            int ci = t + (s & 3);
            int cl = c - 1; if (cl < 0) cl = 0;
            if (ci > cl) ci = cl;
            int2 rr = srec[start + ci];
#pragma unroll
            for (int k = 0; k < 4; ++k) {
                unsigned int o0 = (unsigned)__shfl(rr.x, (h << 4) + k);
                unsigned int o1 = (unsigned)__shfl(rr.y, (h << 4) + k);
                uintx4 a = *(const uintx4*)(g0 + (size_t)o0);
                uintx4 b = *(const uintx4*)(g1 + (size_t)o1);
                bool ok = (t + k) < c;
#pragma unroll
                for (int p = 0; p < 8; ++p) {
                    unsigned int wa = (p & 1) ? (a[p >> 1] & 0xffff0000u)
                                              : (a[p >> 1] << 16);
                    unsigned int wb = (p & 1) ? (b[p >> 1] & 0xffff0000u)
                                              : (b[p >> 1] << 16);
                    float sv = __uint_as_float(wa) + __uint_as_float(wb) + base[p];
                    x[p] += ok ? gelu_fast(sv) : 0.0f;
                }
            }
        }

        // LayerNorm over this row's 128 cols (16 lanes x 8)
        float inv = 1.0f / fmaxf((float)c, 1.0f);
        float sm = 0.0f;
#pragma unroll
        for (int k = 0; k < 8; ++k) { x[k] *= inv; sm += x[k]; }
#pragma unroll
        for (int o = 8; o > 0; o >>= 1) sm += __shfl_xor(sm, o);
        float mu = sm * (1.0f / 128.0f);
        float vv = 0.0f;
#pragma unroll
        for (int k = 0; k < 8; ++k) { x[k] -= mu; vv += x[k] * x[k]; }
#pragma unroll
        for (int o = 8; o > 0; o >>= 1) vv += __shfl_xor(vv, o);
        float rstd = rsqrtf(vv * (1.0f / 128.0f) + 1e-5f);

        if (row < E) {
            float* orow = out + (size_t)row * 128 + s;
#pragma unroll
            for (int k = 0; k < 8; ++k)
                __builtin_nontemporal_store(x[k] * rstd * gm[k] + bt[k],
                                            &orow[k * 16]);
        }
    }
}

extern "C" void kernel_launch(void* const* d_in, const int* in_sizes, int n_in,
                              void* d_out, int out_size, void* d_ws, size_t ws_size,
                              hipStream_t stream)
{
    const float* fe_f  = (const float*)d_in[0];
    const float* Wg    = (const float*)d_in[1];
    const float* bias  = (const float*)d_in[2];
    const float* gamma = (const float*)d_in[3];
    const float* beta  = (const float*)d_in[4];
    const int*   tri   = (const int*)d_in[5];

    int E = in_sizes[0] / 128;
    int T = in_sizes[5] / 3;

    // ws: G (3*E*128 bf16) | srec (T+8 int2) | wq (96KB) | slot (T i32) |
    //     cnt (E) | excl (E) | partial (1024) | pscan (1024) | rowinfo (E int2)
    unsigned short* G = (unsigned short*)d_ws;
    int2* srec = (int2*)((char*)d_ws + (size_t)3 * E * 256);
    uintx4* wq = (uintx4*)(srec + T + 8);
    int* slot = (int*)(wq + 6144);
    int* cnt  = slot + T;
    int* excl = cnt + E;
    int* partial = excl + E;
    int* pscan = partial + 1024;
    int2* rowinfo = (int2*)(pscan + 1024);

    (void)hipMemsetAsync(cnt, 0, (size_t)E * sizeof(int), stream);

    int total = T + 6144;
    prep<<<(total + 255) / 256, 256, 0, stream>>>(Wg, wq, tri, cnt, slot, T);

    int NB = (E + 1023) / 1024;   // 98 for E=100000 (must be <= 1024)
    scan_blk<<<NB, 1024, 0, stream>>>(cnt, excl, partial, E);
    scan_blk<<<1, 1024, 0, stream>>>(partial, pscan, nullptr, NB);

    scatter<<<(T + 255) / 256, 256, 0, stream>>>(tri, slot, excl, pscan, cnt,
                                                 srec, rowinfo, E, T);

    edge_gemm<<<256, 1024, 0, stream>>>(fe_f, wq, G, E);

    mean_ln<<<2048, 256, 0, stream>>>(G, rowinfo, srec, bias, gamma, beta,
                                      (float*)d_out, E);
}